// Round 1
// 310.735 us; speedup vs baseline: 1.0781x; 1.0781x over previous
//
#include <hip/hip_runtime.h>

// x: (8,128,128,128) f32 -> out: (8,128,256,256) f32, 2x upsample + 4x4 FIR.
#define NC    1024            // 8*128 fused
#define H     128
#define W     128
#define OH    256
#define OW    256
#define ROWS  8               // input rows per wave (rolling window)
#define BANDS (H / ROWS)      // 16 bands per image; log2(BANDS) = 4

// 1D collapse of zero-insert-2x + 4-tap FIR (verified in prior round):
//   o even (i=o/2):  K[sy][1]*x[i]   + K[sy][3]*x[i-1]
//   o odd  (i=o/2):  K[sy][0]*x[i+1] + K[sy][2]*x[i]
// Rows: even out row 2r  <- sy=1 @ r,  sy=3 @ r-1
//       odd  out row 2r+1<- sy=2 @ r,  sy=0 @ r+1
//
// Layout: one WAVE covers one full row width. Lane l owns output cols
// 4l..4l+3, so it needs input cols 2l-1..2l+2: a float2 (x[2l],x[2l+1])
// plus one left neighbor (lane l-1's .y) and one right neighbor (lane
// l+1's .x) via 64-wide shuffles. Wave loads = 512B dense per input row;
// wave stores = 1KiB dense per output row (full cachelines, no stride).

struct Row { float L, a, b, R; };

__device__ __forceinline__ Row load_row(const float* __restrict__ base,
                                        int r, int lane) {
    float2 v = make_float2(0.f, 0.f);
    if ((unsigned)r < (unsigned)H)        // wave-uniform predicate
        v = ((const float2*)(base + (size_t)r * W))[lane];
    Row o;
    o.a = v.x;
    o.b = v.y;
    o.L = __shfl_up(v.y, 1, 64);          // x[2l-1]
    o.R = __shfl_down(v.x, 1, 64);        // x[2l+2]
    if (lane == 0)  o.L = 0.f;            // image left border (tap is zero)
    if (lane == 63) o.R = 0.f;            // image right border
    return o;
}

__global__ __launch_bounds__(256) void upscale_kernel(
    const float* __restrict__ x,
    const float* __restrict__ Kp,
    float* __restrict__ out)
{
    const int lane = threadIdx.x & 63;
    const int wave = blockIdx.x * (256 >> 6) + (threadIdx.x >> 6);
    const int band = wave & (BANDS - 1);
    const int nc   = wave >> 4;           // BANDS = 16
    const int r0   = band * ROWS;

    const float* __restrict__ base = x   + (size_t)nc * (H * W);
    float*       __restrict__ ob   = out + (size_t)nc * (OH * OW);

    // 16 kernel weights, uniform address -> scalar loads + broadcast
    const float k00 = Kp[0],  k01 = Kp[1],  k02 = Kp[2],  k03 = Kp[3];
    const float k10 = Kp[4],  k11 = Kp[5],  k12 = Kp[6],  k13 = Kp[7];
    const float k20 = Kp[8],  k21 = Kp[9],  k22 = Kp[10], k23 = Kp[11];
    const float k30 = Kp[12], k31 = Kp[13], k32 = Kp[14], k33 = Kp[15];

    // Rolling 3-row window: m = r-1, c = r, p = r+1. Each input row is
    // loaded exactly once per wave (plus 2 halo rows at the band edges).
    Row m = load_row(base, r0 - 1, lane);
    Row c = load_row(base, r0,     lane);

    #pragma unroll
    for (int i = 0; i < ROWS; ++i) {
        const int r = r0 + i;
        Row p = load_row(base, r + 1, lane);

        float4 oe, oo;
        // even output row 2r: sy=1 @ c, sy=3 @ m
        oe.x = k11 * c.a + k13 * c.L + k31 * m.a + k33 * m.L;  // col 4l   (even)
        oe.y = k10 * c.b + k12 * c.a + k30 * m.b + k32 * m.a;  // col 4l+1 (odd)
        oe.z = k11 * c.b + k13 * c.a + k31 * m.b + k33 * m.a;  // col 4l+2 (even)
        oe.w = k10 * c.R + k12 * c.b + k30 * m.R + k32 * m.b;  // col 4l+3 (odd)
        // odd output row 2r+1: sy=2 @ c, sy=0 @ p
        oo.x = k21 * c.a + k23 * c.L + k01 * p.a + k03 * p.L;
        oo.y = k20 * c.b + k22 * c.a + k00 * p.b + k02 * p.a;
        oo.z = k21 * c.b + k23 * c.a + k01 * p.b + k03 * p.a;
        oo.w = k20 * c.R + k22 * c.b + k00 * p.R + k02 * p.b;

        // Dense stores: lane l -> float4 at byte 16*l; one wave store
        // instruction covers a contiguous 1KiB of one output row.
        ((float4*)(ob + (size_t)(2 * r)     * OW))[lane] = oe;
        ((float4*)(ob + (size_t)(2 * r + 1) * OW))[lane] = oo;

        m = c;
        c = p;
    }
}

extern "C" void kernel_launch(void* const* d_in, const int* in_sizes, int n_in,
                              void* d_out, int out_size, void* d_ws, size_t ws_size,
                              hipStream_t stream) {
    const float* x   = (const float*)d_in[0];
    const float* K   = (const float*)d_in[1];
    float*       out = (float*)d_out;

    // one wave per (image, 8-row band): 1024 * 16 = 16384 waves
    const int total_waves = NC * BANDS;
    dim3 block(256);                       // 4 waves/block
    dim3 grid(total_waves / 4);            // 4096 blocks
    upscale_kernel<<<grid, block, 0, stream>>>(x, K, out);
}

// Round 4
// 306.387 us; speedup vs baseline: 1.0934x; 1.0142x over previous
//
#include <hip/hip_runtime.h>

// x: (8,128,128,128) f32 -> out: (8,128,256,256) f32, 2x upsample + 4x4 FIR.
#define NC    1024            // 8*128 fused
#define H     128
#define W     128
#define OH    256
#define OW    256
#define ROWS  8               // input rows per wave
#define BANDS (H / ROWS)      // 16 bands per image

typedef float v4f __attribute__((ext_vector_type(4)));

// 1D collapse of zero-insert-2x + 4-tap FIR (verified):
//   o even (i=o/2):  K[sy][1]*x[i]   + K[sy][3]*x[i-1]
//   o odd  (i=o/2):  K[sy][0]*x[i+1] + K[sy][2]*x[i]
// Rows: even out row 2r  <- sy=1 @ r,  sy=3 @ r-1
//       odd  out row 2r+1<- sy=2 @ r,  sy=0 @ r+1
//
// One wave = one (image, 8-row band). Lane l owns input cols 2l,2l+1
// (float2) and output cols 4l..4l+3. Horizontal halo via 64-wide shuffle;
// lane 0 / lane 63 edges are the image border (tap is zero there).
// All 10 input-row loads issued up front for MLP; output written with
// non-temporal stores (write-once stream, keep it out of L2).

__global__ __launch_bounds__(256) void upscale_kernel(
    const float* __restrict__ x,
    const float* __restrict__ Kp,
    float* __restrict__ out)
{
    const int lane = threadIdx.x & 63;
    const int wave = blockIdx.x * (256 >> 6) + (threadIdx.x >> 6);
    const int band = wave & (BANDS - 1);
    const int nc   = wave >> 4;           // BANDS = 16
    const int r0   = band * ROWS;

    const float* __restrict__ base = x   + (size_t)nc * (H * W);
    float*       __restrict__ ob   = out + (size_t)nc * (OH * OW);

    // ---- issue all row loads up front (10 independent VMEM ops) ----
    float2 v[ROWS + 2];
    #pragma unroll
    for (int i = 0; i < ROWS + 2; ++i) {
        const int r = r0 - 1 + i;
        v[i] = make_float2(0.f, 0.f);
        if ((unsigned)r < (unsigned)H)    // wave-uniform predicate
            v[i] = ((const float2*)(base + (size_t)r * W))[lane];
    }

    // 16 kernel weights (uniform address -> scalar loads + broadcast)
    const float k00 = Kp[0],  k01 = Kp[1],  k02 = Kp[2],  k03 = Kp[3];
    const float k10 = Kp[4],  k11 = Kp[5],  k12 = Kp[6],  k13 = Kp[7];
    const float k20 = Kp[8],  k21 = Kp[9],  k22 = Kp[10], k23 = Kp[11];
    const float k30 = Kp[12], k31 = Kp[13], k32 = Kp[14], k33 = Kp[15];

    // ---- horizontal halos for every row ----
    float Ls[ROWS + 2], Rs[ROWS + 2];
    const bool le = (lane == 0), re = (lane == 63);
    #pragma unroll
    for (int i = 0; i < ROWS + 2; ++i) {
        float l = __shfl_up(v[i].y, 1, 64);    // x[2l-1]
        float r = __shfl_down(v[i].x, 1, 64);  // x[2l+2]
        Ls[i] = le ? 0.f : l;
        Rs[i] = re ? 0.f : r;
    }

    // ---- compute + non-temporal stores ----
    #pragma unroll
    for (int i = 0; i < ROWS; ++i) {
        const int r = r0 + i;
        const float2 m = v[i],    c = v[i + 1],  p = v[i + 2];
        const float  mL = Ls[i],  cL = Ls[i + 1], pL = Ls[i + 2];
        const float  mR = Rs[i],  cR = Rs[i + 1], pR = Rs[i + 2];

        v4f oe, oo;
        // even output row 2r: sy=1 @ c, sy=3 @ m
        oe.x = k11 * c.x + k13 * cL  + k31 * m.x + k33 * mL;   // col 4l   (even)
        oe.y = k10 * c.y + k12 * c.x + k30 * m.y + k32 * m.x;  // col 4l+1 (odd)
        oe.z = k11 * c.y + k13 * c.x + k31 * m.y + k33 * m.x;  // col 4l+2 (even)
        oe.w = k10 * cR  + k12 * c.y + k30 * mR  + k32 * m.y;  // col 4l+3 (odd)
        // odd output row 2r+1: sy=2 @ c, sy=0 @ p
        oo.x = k21 * c.x + k23 * cL  + k01 * p.x + k03 * pL;
        oo.y = k20 * c.y + k22 * c.x + k00 * p.y + k02 * p.x;
        oo.z = k21 * c.y + k23 * c.x + k01 * p.y + k03 * p.x;
        oo.w = k20 * cR  + k22 * c.y + k00 * pR  + k02 * p.y;

        // Dense 1KiB-per-wave streaming stores, no L2 allocate.
        __builtin_nontemporal_store(oe, ((v4f*)(ob + (size_t)(2 * r)     * OW)) + lane);
        __builtin_nontemporal_store(oo, ((v4f*)(ob + (size_t)(2 * r + 1) * OW)) + lane);
    }
}

extern "C" void kernel_launch(void* const* d_in, const int* in_sizes, int n_in,
                              void* d_out, int out_size, void* d_ws, size_t ws_size,
                              hipStream_t stream) {
    const float* x   = (const float*)d_in[0];
    const float* K   = (const float*)d_in[1];
    float*       out = (float*)d_out;

    // one wave per (image, 8-row band): 1024 * 16 = 16384 waves
    const int total_waves = NC * BANDS;
    dim3 block(256);                       // 4 waves/block
    dim3 grid(total_waves / 4);            // 4096 blocks
    upscale_kernel<<<grid, block, 0, stream>>>(x, K, out);
}

// Round 5
// 304.515 us; speedup vs baseline: 1.1002x; 1.0061x over previous
//
#include <hip/hip_runtime.h>

// x: (8,128,128,128) f32 -> out: (8,128,256,256) f32, 2x upsample + 4x4 FIR.
#define NC    1024            // 8*128 fused
#define H     128
#define W     128
#define OH    256
#define OW    256
#define ROWS  8               // input rows per wave
#define BANDS (H / ROWS)      // 16 bands per image

typedef float v4f  __attribute__((ext_vector_type(4)));
// loads are only dword-aligned (per-lane offset 2l-1): tell the compiler
typedef float v4fa __attribute__((ext_vector_type(4), aligned(4)));

// 1D collapse of zero-insert-2x + 4-tap FIR (verified):
//   o even (i=o/2):  K[sy][1]*x[i]   + K[sy][3]*x[i-1]
//   o odd  (i=o/2):  K[sy][0]*x[i+1] + K[sy][2]*x[i]
// Rows: even out row 2r  <- sy=1 @ r,  sy=3 @ r-1
//       odd  out row 2r+1<- sy=2 @ r,  sy=0 @ r+1
//
// One wave = one (image, 8-row band). Lane l owns output cols 4l..4l+3 and
// loads its FULL tap window per row directly: overlapping float4 covering
// input cols 2l-1..2l+2 (dword-aligned). NO cross-lane shuffles — the DS
// pipe is off the critical path entirely. Lane 0 / lane 63 clamp their
// offset into the row and re-window in registers (cndmask), so no access
// ever leaves the row. Output: dense 1KiB-per-wave NT stores.

__global__ __launch_bounds__(256) void upscale_kernel(
    const float* __restrict__ x,
    const float* __restrict__ Kp,
    float* __restrict__ out)
{
    const int lane = threadIdx.x & 63;
    const int wave = blockIdx.x * (256 >> 6) + (threadIdx.x >> 6);
    const int band = wave & (BANDS - 1);
    const int nc   = wave >> 4;           // BANDS = 16
    const int r0   = band * ROWS;

    const float* __restrict__ base = x   + (size_t)nc * (H * W);
    float*       __restrict__ ob   = out + (size_t)nc * (OH * OW);

    // per-lane float offset of the tap window inside a row, clamped in-row
    int fo = 2 * lane - 1;
    fo = fo < 0 ? 0 : (fo > W - 4 ? W - 4 : fo);
    const bool le = (lane == 0), re = (lane == 63);

    // ---- all 10 row loads up front (independent VMEM, max MLP) ----
    // v[i] = (L, a, b, R) = x[r][2l-1], x[r][2l], x[r][2l+1], x[r][2l+2]
    v4f v[ROWS + 2];
    #pragma unroll
    for (int i = 0; i < ROWS + 2; ++i) {
        const int r = r0 - 1 + i;
        v4f t = {0.f, 0.f, 0.f, 0.f};
        if ((unsigned)r < (unsigned)H)    // wave-uniform predicate
            t = *(const v4fa*)(base + (size_t)r * W + fo);
        // lane 0 loaded cols 0..3, wants (0, c0, c1, c2);
        // lane 63 loaded cols 124..127, wants (c125, c126, c127, 0)
        v4f u;
        u.x = le ? 0.f : (re ? t.y : t.x);
        u.y = le ? t.x : (re ? t.z : t.y);
        u.z = le ? t.y : (re ? t.w : t.z);
        u.w = le ? t.z : (re ? 0.f : t.w);
        v[i] = u;
    }

    // 16 kernel weights: uniform address -> scalar loads, SGPR broadcast
    const float k00 = Kp[0],  k01 = Kp[1],  k02 = Kp[2],  k03 = Kp[3];
    const float k10 = Kp[4],  k11 = Kp[5],  k12 = Kp[6],  k13 = Kp[7];
    const float k20 = Kp[8],  k21 = Kp[9],  k22 = Kp[10], k23 = Kp[11];
    const float k30 = Kp[12], k31 = Kp[13], k32 = Kp[14], k33 = Kp[15];

    // ---- compute + non-temporal stores ----
    #pragma unroll
    for (int i = 0; i < ROWS; ++i) {
        const int r = r0 + i;
        const v4f m = v[i], c = v[i + 1], p = v[i + 2];

        v4f oe, oo;
        // even output row 2r: sy=1 @ c, sy=3 @ m   (.x=L .y=a .z=b .w=R)
        oe.x = k11 * c.y + k13 * c.x + k31 * m.y + k33 * m.x;  // col 4l   (even)
        oe.y = k10 * c.z + k12 * c.y + k30 * m.z + k32 * m.y;  // col 4l+1 (odd)
        oe.z = k11 * c.z + k13 * c.y + k31 * m.z + k33 * m.y;  // col 4l+2 (even)
        oe.w = k10 * c.w + k12 * c.z + k30 * m.w + k32 * m.z;  // col 4l+3 (odd)
        // odd output row 2r+1: sy=2 @ c, sy=0 @ p
        oo.x = k21 * c.y + k23 * c.x + k01 * p.y + k03 * p.x;
        oo.y = k20 * c.z + k22 * c.y + k00 * p.z + k02 * p.y;
        oo.z = k21 * c.z + k23 * c.y + k01 * p.z + k03 * p.y;
        oo.w = k20 * c.w + k22 * c.z + k00 * p.w + k02 * p.z;

        // Dense 1KiB-per-wave streaming stores.
        __builtin_nontemporal_store(oe, ((v4f*)(ob + (size_t)(2 * r)     * OW)) + lane);
        __builtin_nontemporal_store(oo, ((v4f*)(ob + (size_t)(2 * r + 1) * OW)) + lane);
    }
}

extern "C" void kernel_launch(void* const* d_in, const int* in_sizes, int n_in,
                              void* d_out, int out_size, void* d_ws, size_t ws_size,
                              hipStream_t stream) {
    const float* x   = (const float*)d_in[0];
    const float* K   = (const float*)d_in[1];
    float*       out = (float*)d_out;

    // one wave per (image, 8-row band): 1024 * 16 = 16384 waves
    const int total_waves = NC * BANDS;
    dim3 block(256);                       // 4 waves/block
    dim3 grid(total_waves / 4);            // 4096 blocks
    upscale_kernel<<<grid, block, 0, stream>>>(x, K, out);
}